// Round 6
// baseline (124.503 us; speedup 1.0000x reference)
//
#include <hip/hip_runtime.h>
#include <hip/hip_bf16.h>
#include <math.h>

// S5 SSM layer. B_SZ=16, L=1024, H=256, P=256.
// R16: ONE dispatch, 2 tree barriers, NO staging pipeline:
//  - B operands (W1/W2, L2-resident) loaded per-wave DIRECT to registers (no LDS,
//    no async DMA, no per-k-step barriers -> GEMM loops are barrier-free).
//  - A (u tile) loaded ONCE to LDS at kernel start (XOR-swizzled rows), HBM
//    latency hidden under prep + bar0. GEMM2 A = X in LDS (stride 520 shorts).
// Phases: u-preload+prep -> [bar0] -> GEMM1 -> X dump -> scan -> [bar1] ->
//         in-block prefix -> fixup -> GEMM2 + D*u.
#define BB     16
#define LSEQ   1024
#define HH     256
#define PP     256
#define LC     32
#define NC     (LSEQ/LC)     // 32
#define NCHUNK (BB*NC)       // 512

// workspace byte offsets
#define OFF_W1T  0u          // [512][256] bf16: row 2p=Re(B_bar[p][.]), 2p+1=Im
#define OFF_W2T  262144u     // [256][512] bf16: row h, k=2p -> 2*C_re, 2p+1 -> -2*C_im
#define OFF_PW   524288u     // [33][256] float2: lambda_bar^t
#define OFF_CEND 655360u     // [512][256] float2 chunk-end local states (1 MB)
#define OFF_BAR  2752512u    // tree-barrier area: 2 instances x 8192 B (memset each launch)

typedef __attribute__((ext_vector_type(8))) short short8;
typedef __attribute__((ext_vector_type(4))) float floatx4;
typedef unsigned long long ull;

__device__ __forceinline__ float bf2f(unsigned hs) {
    union { unsigned u; float f; } v; v.u = hs << 16; return v.f;
}
__device__ __forceinline__ unsigned short f2bs(float f) {
    __hip_bfloat16 h = __float2bfloat16(f);
    union { __hip_bfloat16 h; unsigned short s; } v; v.h = h; return v.s;
}
__device__ __forceinline__ unsigned packbf(float r, float i) {
    return (unsigned)f2bs(r) | ((unsigned)f2bs(i) << 16);
}
__device__ __forceinline__ float2 lam_pow(float lr, float li, float dtt) {
    float m = expf(lr * dtt);
    return make_float2(m * cosf(li * dtt), m * sinf(li * dtt));
}
__device__ __forceinline__ void cohst32(unsigned* p, unsigned v) {
    __hip_atomic_store(p, v, __ATOMIC_RELAXED, __HIP_MEMORY_SCOPE_AGENT);
}
__device__ __forceinline__ void cohst64(ull* p, float2 v) {
    ull b; __builtin_memcpy(&b, &v, 8);
    __hip_atomic_store(p, b, __ATOMIC_RELAXED, __HIP_MEMORY_SCOPE_AGENT);
}

// Two-level grid barrier, no cache fences (all cross-block data uses sc1 stores).
// Groups of 16 blocks -> per-group counter (own cacheline); 32 group leaders ->
// root counter; release root_flag -> group_flags. Max same-line pollers: 31.
__device__ __forceinline__ void treebar(char* base, int inst) {
    asm volatile("s_waitcnt vmcnt(0)" ::: "memory");   // prior sc1 stores done
    __syncthreads();
    if (threadIdx.x == 0) {
        char* b = base + inst * 8192;
        const unsigned g = blockIdx.x >> 4;            // 32 groups of 16
        unsigned* gcnt  = (unsigned*)(b + g * 64);
        unsigned* gflag = (unsigned*)(b + 2048 + g * 64);
        unsigned* rcnt  = (unsigned*)(b + 4096);
        unsigned* rflag = (unsigned*)(b + 4160);
        unsigned r = __hip_atomic_fetch_add(gcnt, 1u, __ATOMIC_RELAXED,
                                            __HIP_MEMORY_SCOPE_AGENT);
        if (r == 15) {                                 // last arriver = leader
            unsigned rr = __hip_atomic_fetch_add(rcnt, 1u, __ATOMIC_RELAXED,
                                                 __HIP_MEMORY_SCOPE_AGENT);
            if (rr == 31) {
                __hip_atomic_store(rflag, 1u, __ATOMIC_RELAXED, __HIP_MEMORY_SCOPE_AGENT);
            } else {
                for (int it = 0; it < (1 << 18); ++it) {   // bounded: no hang
                    if (__hip_atomic_load(rflag, __ATOMIC_RELAXED, __HIP_MEMORY_SCOPE_AGENT))
                        break;
                    __builtin_amdgcn_s_sleep(4);
                }
            }
            __hip_atomic_store(gflag, 1u, __ATOMIC_RELAXED, __HIP_MEMORY_SCOPE_AGENT);
        } else {
            for (int it = 0; it < (1 << 18); ++it) {
                if (__hip_atomic_load(gflag, __ATOMIC_RELAXED, __HIP_MEMORY_SCOPE_AGENT))
                    break;
                __builtin_amdgcn_s_sleep(4);
            }
        }
    }
    __syncthreads();
}

// LDS map (35328 B total, 2 blocks/CU):
//   phase GEMM1 : A @0   [32 rows][512 B] bf16, k-byte XOR-swizzled by (row&7)<<4 (16 KB)
//   phase scan+ : X @0   [32][520] bf16 (33280 B; stride 520 -> (rr+q)%8 bank slots)
//                 carrs @33280  [256] float2 (2 KB)
#define XSTRS 520
#define XSTRD 260
#define CARR_OFF 33280

__global__ __launch_bounds__(512, 4) void k_all(
        const float* __restrict__ u, const float* __restrict__ Lr,
        const float* __restrict__ Li, const float* __restrict__ ls,
        const float* __restrict__ Bm, const float* __restrict__ Cm,
        const float* __restrict__ D, float* __restrict__ out,
        char* __restrict__ ws) {
    extern __shared__ char smem[];
    char* barbase = ws + OFF_BAR;

    const int tid = threadIdx.x, bc = blockIdx.x;
    const int wave = tid >> 6, lane = tid & 63;
    const int q = lane >> 4, rr = lane & 15;
    const int m0 = bc * LC;

    // ---- u tile preload: issue HBM loads FIRST (latency hides under prep+bar0) --
    const int arow = tid >> 4, acol = (tid & 15) * 16;   // 16 f32 elems/thread
    float4 uv[4];
    {
        const float* up = u + (size_t)(m0 + arow) * 256 + acol;
        #pragma unroll
        for (int i = 0; i < 4; ++i) uv[i] = *(const float4*)(up + 4 * i);
    }

    // ---------------- phase 0: prep (W1T, PW, W2T) via coherent stores ----------
    if (bc < 256) {
        if (tid < 128) {
            int p = bc, t = tid;
            float lr = Lr[p], li = Li[p];
            float dt = expf(ls[p]);
            float2 lam = lam_pow(lr, li, dt);
            float den = lr * lr + li * li;
            float nr = lam.x - 1.0f, ni = lam.y;
            float cr = (nr * lr + ni * li) / den;    // (lam_bar-1)/Lambda
            float ci = (ni * lr - nr * li) / den;
            float4 bv = *(const float4*)(Bm + (size_t)p * 512 + 4 * t);
            unsigned rev = packbf(cr * bv.x - ci * bv.y, cr * bv.z - ci * bv.w);
            unsigned imv = packbf(cr * bv.y + ci * bv.x, cr * bv.w + ci * bv.z);
            unsigned* w1u = (unsigned*)(ws + OFF_W1T);
            cohst32(&w1u[(2 * p) * 128 + t], rev);
            cohst32(&w1u[(2 * p + 1) * 128 + t], imv);
            if (t <= 32)
                cohst64((ull*)(ws + OFF_PW) + (size_t)t * 256 + p,
                        lam_pow(lr, li, dt * (float)t));
        }
    } else {
        if (tid < 256) {
            int h = bc - 256, p = tid;
            float c_r = Cm[(h * PP + p) * 2 + 0];
            float c_i = Cm[(h * PP + p) * 2 + 1];
            cohst32((unsigned*)(ws + OFF_W2T) + h * 256 + p, packbf(2.0f * c_r, -2.0f * c_i));
        }
    }

    // ---- pack u -> bf16 into swizzled LDS A (published by bar0's syncthreads) ---
    {
        unsigned pk[8];
        #pragma unroll
        for (int i = 0; i < 4; ++i) {
            pk[2 * i]     = packbf(uv[i].x, uv[i].y);
            pk[2 * i + 1] = packbf(uv[i].z, uv[i].w);
        }
        const int kb = acol * 2;                   // k-byte base (32 B/thread)
        const int msk = (arow & 7) << 4;
        char* A = smem;
        *(uint4*)(A + arow * 512 + (kb ^ msk))        = make_uint4(pk[0], pk[1], pk[2], pk[3]);
        *(uint4*)(A + arow * 512 + ((kb + 16) ^ msk)) = make_uint4(pk[4], pk[5], pk[6], pk[7]);
    }
    treebar(barbase, 0);           // W1T/PW/W2T coherent; LDS A visible

    // ---------------- phase 1: GEMM1 (BM=32, BN=512, K=256), barrier-free -------
    // A from swizzled LDS; B fragments DIRECT from L2-resident W1 to registers.
    {
        const char* W1 = (const char*)(ws + OFF_W1T);
        const char* A = smem;
        const int amask = (rr & 7) << 4;
        floatx4 acc[2][4];
        #pragma unroll
        for (int i = 0; i < 2; ++i)
            #pragma unroll
            for (int j = 0; j < 4; ++j) acc[i][j] = (floatx4)0.0f;

        #pragma unroll 2
        for (int hs = 0; hs < 8; ++hs) {
            const int kb = hs * 64 + q * 16;
            short8 a0 = *(const short8*)(A + rr * 512 + (kb ^ amask));
            short8 a1 = *(const short8*)(A + (16 + rr) * 512 + (kb ^ amask));
            #pragma unroll
            for (int j = 0; j < 4; ++j) {
                short8 b = *(const short8*)(W1 + (size_t)(wave * 64 + j * 16 + rr) * 512 + kb);
                acc[0][j] = __builtin_amdgcn_mfma_f32_16x16x32_bf16(a0, b, acc[0][j], 0, 0, 0);
                acc[1][j] = __builtin_amdgcn_mfma_f32_16x16x32_bf16(a1, b, acc[1][j], 0, 0, 0);
            }
        }
        __syncthreads();           // all waves done with LDS A before X overwrites it
        // dump Bu tile (32 x 512) into padded LDS X
        unsigned short* X = (unsigned short*)smem;
        #pragma unroll
        for (int i = 0; i < 2; ++i)
            #pragma unroll
            for (int j = 0; j < 4; ++j)
                #pragma unroll
                for (int r0 = 0; r0 < 4; ++r0)
                    X[(i * 16 + q * 4 + r0) * XSTRS + wave * 64 + j * 16 + rr] =
                        f2bs(acc[i][j][r0]);
        __syncthreads();
    }

    // ---------------- phase 2: local scan (waves 0-3; 256 channel pairs) --------
    if (tid < 256) {
        const int pq = tid;
        const float2 lam = lam_pow(Lr[pq], Li[pq], expf(ls[pq]));
        unsigned* X32 = (unsigned*)smem;
        float xr = 0.0f, xi = 0.0f;
        #pragma unroll
        for (int j = 0; j < LC; ++j) {
            unsigned cv = X32[j * XSTRD + pq];
            float br = bf2f(cv & 0xffffu), bi = bf2f(cv >> 16);
            float nr = fmaf(lam.x, xr, fmaf(-lam.y, xi, br));
            float ni = fmaf(lam.x, xi, fmaf(lam.y, xr, bi));
            xr = nr; xi = ni;
            X32[j * XSTRD + pq] = packbf(xr, xi);   // x_local in place
        }
        cohst64((ull*)(ws + OFF_CEND) + (size_t)bc * 256 + pq, make_float2(xr, xi));
    }
    treebar(barbase, 1);           // CEND at coherent point

    // ---------------- phase 3: per-block carry via fixed-31 predicated prefix ----
    // carry_c = sum_{k=0}^{c-1} g^k * e_{c-1-k};  masked terms contribute exact 0.
    {
        float2* carrs = (float2*)(smem + CARR_OFF);
        if (tid < 256) {
            const int p = tid;
            const int c = bc & (NC - 1);         // chunk index within batch
            const int b0 = bc & ~(NC - 1);       // first chunk of this batch
            const float2* cend = (const float2*)(ws + OFF_CEND);
            const float2 g = lam_pow(Lr[p], Li[p], expf(ls[p]) * (float)LC);
            float sr = 0.0f, si = 0.0f;
            float gpr = 1.0f, gpi = 0.0f;        // g^k
            #pragma unroll
            for (int k = 0; k < NC - 1; ++k) {   // fixed trip count -> pipelined loads
                int idx = c - 1 - k; idx = idx < 0 ? 0 : idx;
                float2 e = cend[(size_t)(b0 + idx) * 256 + p];
                float er = (k < c) ? e.x : 0.0f;
                float ei = (k < c) ? e.y : 0.0f;
                sr = fmaf(gpr, er, fmaf(-gpi, ei, sr));
                si = fmaf(gpr, ei, fmaf(gpi, er, si));
                float t2 = gpr * g.x - gpi * g.y;
                gpi = gpr * g.y + gpi * g.x; gpr = t2;
            }
            carrs[p] = make_float2(sr, si);
        }
        __syncthreads();
    }

    // ---------------- phase 4: fixup X in place ----------------------------------
    {
        float2* carrs = (float2*)(smem + CARR_OFF);
        unsigned* X32 = (unsigned*)smem;
        const float2* pw = (const float2*)(ws + OFF_PW);
        const int frow = tid >> 4, fcol = tid & 15;
        const float2* pwr = pw + (size_t)(frow + 1) * 256;
        #pragma unroll 4
        for (int e = 0; e < 16; ++e) {
            int p = fcol + e * 16;
            unsigned cv = X32[frow * XSTRD + p];
            float2 pwv = pwr[p];
            float2 cav = carrs[p];
            float fr = pwv.x * cav.x - pwv.y * cav.y;
            float fi = pwv.x * cav.y + pwv.y * cav.x;
            X32[frow * XSTRD + p] =
                packbf(bf2f(cv & 0xffffu) + fr, bf2f(cv >> 16) + fi);
        }
        __syncthreads();
    }

    // ---------------- phase 5: GEMM2 (BM=32, BN=256, K=512), barrier-free -------
    // A from LDS X; B fragments DIRECT from L2-resident W2 to registers.
    {
        const char* W2 = (const char*)(ws + OFF_W2T);
        const char* Xb = (const char*)smem;
        floatx4 acc[2][2];
        #pragma unroll
        for (int i = 0; i < 2; ++i)
            #pragma unroll
            for (int j = 0; j < 2; ++j) acc[i][j] = (floatx4)0.0f;

        #pragma unroll 2
        for (int hs = 0; hs < 16; ++hs) {
            const int kb = hs * 64 + q * 16;
            short8 a[2], bfr[2];
            #pragma unroll
            for (int i = 0; i < 2; ++i)
                a[i] = *(const short8*)(Xb + (i * 16 + rr) * (XSTRS * 2) + kb);
            #pragma unroll
            for (int j = 0; j < 2; ++j)
                bfr[j] = *(const short8*)(W2 + (size_t)(wave * 32 + j * 16 + rr) * 1024 + kb);
            #pragma unroll
            for (int i = 0; i < 2; ++i)
                #pragma unroll
                for (int j = 0; j < 2; ++j)
                    acc[i][j] = __builtin_amdgcn_mfma_f32_16x16x32_bf16(a[i], bfr[j], acc[i][j], 0, 0, 0);
        }

        #pragma unroll
        for (int i = 0; i < 2; ++i) {
            int mbase = m0 + i * 16 + q * 4;
            #pragma unroll
            for (int j = 0; j < 2; ++j) {
                int col = wave * 32 + j * 16 + rr;
                #pragma unroll
                for (int r0 = 0; r0 < 4; ++r0) {
                    int rw = mbase + r0;
                    size_t gi = (size_t)rw * 256 + col;
                    out[gi] = acc[i][j][r0] + D[col] * u[gi];
                }
            }
        }
    }
}

extern "C" void kernel_launch(void* const* d_in, const int* in_sizes, int n_in,
                              void* d_out, int out_size, void* d_ws, size_t ws_size,
                              hipStream_t stream) {
    const float* u  = (const float*)d_in[0];
    const float* Lr = (const float*)d_in[1];
    const float* Li = (const float*)d_in[2];
    const float* Bm = (const float*)d_in[3];
    const float* Cm = (const float*)d_in[4];
    const float* D  = (const float*)d_in[5];
    const float* ls = (const float*)d_in[6];
    float* out = (float*)d_out;
    char* ws = (char*)d_ws;

    // zero both tree-barrier instances (workspace is re-poisoned before every launch)
    hipMemsetAsync(ws + OFF_BAR, 0, 16384, stream);
    k_all<<<NCHUNK, 512, 35328, stream>>>(u, Lr, Li, ls, Bm, Cm, D, out, ws);
}

// Round 8
// 103.983 us; speedup vs baseline: 1.1973x; 1.1973x over previous
//
#include <hip/hip_runtime.h>
#include <hip/hip_bf16.h>
#include <math.h>

// S5 SSM layer. B_SZ=16, L=1024, H=256, P=256.
// R18: k_prep -> k_main. GEMM loops BARRIER-FREE:
//  - each wave stages its OWN B-row slice (wave-private) -> no cross-wave hazard,
//    sync = own-wave vmcnt(0) only. Double buffers correctly sized (G1: 2x32KB).
//  - B chunk-XOR swizzle (pos ^ ((row>>1)&3)), applied at global src + read ->
//    2-way max on ds_read_b128 (free).  A (u) in XOR-swizzled LDS as R16/17.
//  - batch-scoped barrier (32 blocks) before carry prefix.
#define BB     16
#define LSEQ   1024
#define HH     256
#define PP     256
#define LC     32
#define NC     (LSEQ/LC)     // 32
#define NCHUNK (BB*NC)       // 512

// workspace byte offsets
#define OFF_W1T  0u          // [512][256] bf16: row 2p=Re(B_bar[p][.]), 2p+1=Im
#define OFF_W2T  262144u     // [256][512] bf16: row h, k=2p -> 2*C_re, 2p+1 -> -2*C_im
#define OFF_PW   524288u     // [33][256] float2: lambda_bar^t
#define OFF_CEND 655360u     // [512][256] float2 chunk-end local states (1 MB)
#define OFF_BAR  2752512u    // batch-barrier area (zeroed by k_prep block 0)

typedef __attribute__((ext_vector_type(8))) short short8;
typedef __attribute__((ext_vector_type(4))) float floatx4;
typedef unsigned long long ull;

__device__ __forceinline__ float bf2f(unsigned hs) {
    union { unsigned u; float f; } v; v.u = hs << 16; return v.f;
}
__device__ __forceinline__ unsigned short f2bs(float f) {
    __hip_bfloat16 h = __float2bfloat16(f);
    union { __hip_bfloat16 h; unsigned short s; } v; v.h = h; return v.s;
}
__device__ __forceinline__ unsigned packbf(float r, float i) {
    return (unsigned)f2bs(r) | ((unsigned)f2bs(i) << 16);
}
__device__ __forceinline__ void async16(const void* g, void* l) {
    __builtin_amdgcn_global_load_lds(
        (const __attribute__((address_space(1))) unsigned*)g,
        (__attribute__((address_space(3))) unsigned*)l, 16, 0, 0);
}
__device__ __forceinline__ float2 lam_pow(float lr, float li, float dtt) {
    float m = expf(lr * dtt);
    return make_float2(m * cosf(li * dtt), m * sinf(li * dtt));
}
__device__ __forceinline__ void cohst64(ull* p, float2 v) {
    ull b; __builtin_memcpy(&b, &v, 8);
    __hip_atomic_store(p, b, __ATOMIC_RELAXED, __HIP_MEMORY_SCOPE_AGENT);
}

// Batch-scope barrier: 32 blocks of one batch (bc>>5). No cache fences —
// CEND uses sc1 stores (coherent at L3); vmcnt(0) drains them pre-arrival.
__device__ __forceinline__ void batchbar(char* base) {
    asm volatile("s_waitcnt vmcnt(0)" ::: "memory");
    __syncthreads();
    if (threadIdx.x == 0) {
        const unsigned b = blockIdx.x >> 5;
        unsigned* cnt  = (unsigned*)(base + b * 64);
        unsigned* flag = (unsigned*)(base + 2048 + b * 64);
        if (__hip_atomic_fetch_add(cnt, 1u, __ATOMIC_RELAXED,
                                   __HIP_MEMORY_SCOPE_AGENT) == 31u) {
            __hip_atomic_store(flag, 1u, __ATOMIC_RELAXED, __HIP_MEMORY_SCOPE_AGENT);
        } else {
            for (int it = 0; it < (1 << 18); ++it) {   // bounded: no hang
                if (__hip_atomic_load(flag, __ATOMIC_RELAXED, __HIP_MEMORY_SCOPE_AGENT))
                    break;
                __builtin_amdgcn_s_sleep(2);
            }
        }
    }
    __syncthreads();
}

// ---------------- k_prep: W1T/PW (blocks 0..255), W2T (256..511), bar init ------
__global__ void k_prep(const float* __restrict__ Bm, const float* __restrict__ Cm,
                       const float* __restrict__ Lr, const float* __restrict__ Li,
                       const float* __restrict__ ls, char* __restrict__ ws) {
    int blk = blockIdx.x, t = threadIdx.x;
    if (blk < 256) {
        if (t < 128) {
            int p = blk;
            float lr = Lr[p], li = Li[p];
            float dt = expf(ls[p]);
            float2 lam = lam_pow(lr, li, dt);
            float den = lr * lr + li * li;
            float nr = lam.x - 1.0f, ni = lam.y;
            float cr = (nr * lr + ni * li) / den;    // (lam_bar-1)/Lambda
            float ci = (ni * lr - nr * li) / den;
            float4 bv = *(const float4*)(Bm + (size_t)p * 512 + 4 * t);
            unsigned* w1u = (unsigned*)(ws + OFF_W1T);
            w1u[(2 * p) * 128 + t]     = packbf(cr * bv.x - ci * bv.y, cr * bv.z - ci * bv.w);
            w1u[(2 * p + 1) * 128 + t] = packbf(cr * bv.y + ci * bv.x, cr * bv.w + ci * bv.z);
            if (t <= 32)
                ((float2*)(ws + OFF_PW))[t * 256 + p] = lam_pow(lr, li, dt * (float)t);
        }
        if (blk == 0)   // zero batch-barrier area (4 KB)
            ((float4*)(ws + OFF_BAR))[t] = make_float4(0.f, 0.f, 0.f, 0.f);
    } else {
        int h = blk - 256, p = t;
        float c_r = Cm[(h * PP + p) * 2 + 0];
        float c_i = Cm[(h * PP + p) * 2 + 1];
        ((unsigned*)(ws + OFF_W2T))[h * 256 + p] = packbf(2.0f * c_r, -2.0f * c_i);
    }
}

// LDS map (81920 B, 2 blocks/CU = 160 KB exactly):
//   GEMM1 : A  @0      [32 rows][512 B] bf16, k-byte XOR-swizzled by (row&7)<<4
//           B1 @16384  2 bufs x 32768 B ([8 waves][64 rows][64 B], chunk-swizzled)
//   later : X  @0      [32][520] bf16 (33280 B)
//           carrs @33280 [256] float2 (2 KB)
//           B2 @35328  2 bufs x 16384 B ([8 waves][32 rows][64 B], chunk-swizzled)
#define XSTRS 520
#define XSTRD 260
#define CARR_OFF 33280
#define B1_OFF  16384
#define B2_OFF  35328

__global__ __launch_bounds__(512, 4) void k_main(
        const float* __restrict__ u, const float* __restrict__ Lr,
        const float* __restrict__ Li, const float* __restrict__ ls,
        const float* __restrict__ D, float* __restrict__ out,
        char* __restrict__ ws) {
    extern __shared__ char smem[];
    const int tid = threadIdx.x, bc = blockIdx.x;
    const int wave = tid >> 6, lane = tid & 63;
    const int q = lane >> 4, rr = lane & 15;
    const int m0 = bc * LC;
    const int fs = (lane >> 3) & 3;          // staging swizzle = (R>>1)&3 for own slot
    const int fr = (rr >> 1) & 3;            // read swizzle    = (R>>1)&3 for own row

    // ---- GEMM1 panel-0 DMA first (wave-private slice; flies under u-load/pack) --
    {
        const char* W1 = (const char*)(ws + OFF_W1T);
        char* dst = smem + B1_OFF + wave * 4096;
        #pragma unroll
        for (int i = 0; i < 4; ++i) {
            int n = i * 64 + lane;                       // slot in own 4 KB slice
            int R = wave * 64 + (n >> 2);                // global B-row
            async16(W1 + (size_t)R * 512 + (((n & 3) ^ fs) << 4), dst + n * 16);
        }
    }

    // ---- u tile preload + pack -> bf16 into swizzled LDS A ----------------------
    const int arow = tid >> 4, acol = (tid & 15) * 16;   // 16 f32 elems/thread
    {
        float4 uv[4];
        const float* up = u + (size_t)(m0 + arow) * 256 + acol;
        #pragma unroll
        for (int i = 0; i < 4; ++i) uv[i] = *(const float4*)(up + 4 * i);
        unsigned pk[8];
        #pragma unroll
        for (int i = 0; i < 4; ++i) {
            pk[2 * i]     = packbf(uv[i].x, uv[i].y);
            pk[2 * i + 1] = packbf(uv[i].z, uv[i].w);
        }
        const int kb = acol * 2;                   // k-byte base (32 B/thread)
        const int msk = (arow & 7) << 4;
        char* A = smem;
        *(uint4*)(A + arow * 512 + (kb ^ msk))        = make_uint4(pk[0], pk[1], pk[2], pk[3]);
        *(uint4*)(A + arow * 512 + ((kb + 16) ^ msk)) = make_uint4(pk[4], pk[5], pk[6], pk[7]);
    }
    __syncthreads();                           // A visible to all waves

    // ---------------- GEMM1 (BM=32, BN=512, K=256), 8 panels BK=32 ---------------
    // Barrier-free: wave reads only its own staged slice.
    {
        const char* W1 = (const char*)(ws + OFF_W1T);
        const char* A = smem;
        const int amask = (rr & 7) << 4;
        floatx4 acc[2][4];
        #pragma unroll
        for (int i = 0; i < 2; ++i)
            #pragma unroll
            for (int j = 0; j < 4; ++j) acc[i][j] = (floatx4)0.0f;

        for (int t = 0; t < 8; ++t) {
            asm volatile("s_waitcnt vmcnt(0)" ::: "memory");   // own panel-t landed
            if (t < 7) {    // issue own slice of panel t+1 under this panel's MFMAs
                char* dst = smem + B1_OFF + ((t + 1) & 1) * 32768 + wave * 4096;
                const char* src = W1 + (t + 1) * 64;
                #pragma unroll
                for (int i = 0; i < 4; ++i) {
                    int n = i * 64 + lane;
                    int R = wave * 64 + (n >> 2);
                    async16(src + (size_t)R * 512 + (((n & 3) ^ fs) << 4), dst + n * 16);
                }
            }
            const char* bb = smem + B1_OFF + (t & 1) * 32768 + wave * 4096;
            const int kbA = t * 64 + q * 16;
            short8 a0 = *(const short8*)(A + rr * 512 + (kbA ^ amask));
            short8 a1 = *(const short8*)(A + (16 + rr) * 512 + (kbA ^ amask));
            #pragma unroll
            for (int j = 0; j < 4; ++j) {
                short8 b = *(const short8*)(bb + (j * 16 + rr) * 64 + ((q ^ fr) << 4));
                acc[0][j] = __builtin_amdgcn_mfma_f32_16x16x32_bf16(a0, b, acc[0][j], 0, 0, 0);
                acc[1][j] = __builtin_amdgcn_mfma_f32_16x16x32_bf16(a1, b, acc[1][j], 0, 0, 0);
            }
        }
        __syncthreads();                       // all waves done with A/B1
        // dump Bu tile (32 x 512) into padded LDS X (overwrites A + B1 head)
        unsigned short* X = (unsigned short*)smem;
        #pragma unroll
        for (int i = 0; i < 2; ++i)
            #pragma unroll
            for (int j = 0; j < 4; ++j)
                #pragma unroll
                for (int r0 = 0; r0 < 4; ++r0)
                    X[(i * 16 + q * 4 + r0) * XSTRS + wave * 64 + j * 16 + rr] =
                        f2bs(acc[i][j][r0]);
        __syncthreads();
    }

    // ---------------- local scan (waves 0-3) || GEMM2 panel-0 prestage (4-7) -----
    if (tid < 256) {
        const int pq = tid;
        const float2 lam = lam_pow(Lr[pq], Li[pq], expf(ls[pq]));
        unsigned* X32 = (unsigned*)smem;
        float xr = 0.0f, xi = 0.0f;
        #pragma unroll
        for (int j = 0; j < LC; ++j) {
            unsigned cv = X32[j * XSTRD + pq];
            float br = bf2f(cv & 0xffffu), bi = bf2f(cv >> 16);
            float nr = fmaf(lam.x, xr, fmaf(-lam.y, xi, br));
            float ni = fmaf(lam.x, xi, fmaf(lam.y, xr, bi));
            xr = nr; xi = ni;
            X32[j * XSTRD + pq] = packbf(xr, xi);   // x_local in place
        }
        cohst64((ull*)(ws + OFF_CEND) + (size_t)bc * 256 + pq, make_float2(xr, xi));
    } else {
        // prestage FULL GEMM2 panel 0 (all waves' slices) while the scan runs
        const char* W2 = (const char*)(ws + OFF_W2T);
        char* B2 = smem + B2_OFF;
        const int t4 = tid - 256;
        const int f0 = (t4 >> 3) & 3;
        #pragma unroll
        for (int i = 0; i < 4; ++i) {
            int c = i * 256 + t4;                  // linear slot 0..1023
            int R = c >> 2;                        // global B-row 0..255
            async16(W2 + (size_t)R * 1024 + (((c & 3) ^ f0) << 4), B2 + c * 16);
        }
    }
    batchbar(ws + OFF_BAR);        // this batch's CEND coherent; panel 0 visible

    // ---------------- per-block carry via fixed-31 predicated prefix -------------
    {
        float2* carrs = (float2*)(smem + CARR_OFF);
        if (tid < 256) {
            const int p = tid;
            const int c = bc & (NC - 1);
            const int b0 = bc & ~(NC - 1);
            const float2* cend = (const float2*)(ws + OFF_CEND);
            const float2 g = lam_pow(Lr[p], Li[p], expf(ls[p]) * (float)LC);
            float sr = 0.0f, si = 0.0f;
            float gpr = 1.0f, gpi = 0.0f;
            #pragma unroll
            for (int k = 0; k < NC - 1; ++k) {
                int idx = c - 1 - k; idx = idx < 0 ? 0 : idx;
                float2 e = cend[(size_t)(b0 + idx) * 256 + p];
                float er = (k < c) ? e.x : 0.0f;
                float ei = (k < c) ? e.y : 0.0f;
                sr = fmaf(gpr, er, fmaf(-gpi, ei, sr));
                si = fmaf(gpr, ei, fmaf(gpi, er, si));
                float t2 = gpr * g.x - gpi * g.y;
                gpi = gpr * g.y + gpi * g.x; gpr = t2;
            }
            carrs[p] = make_float2(sr, si);
        }
        __syncthreads();
    }

    // ---------------- fixup X in place -------------------------------------------
    {
        float2* carrs = (float2*)(smem + CARR_OFF);
        unsigned* X32 = (unsigned*)smem;
        const float2* pw = (const float2*)(ws + OFF_PW);
        const int frow = tid >> 4, fcol = tid & 15;
        const float2* pwr = pw + (size_t)(frow + 1) * 256;
        #pragma unroll 4
        for (int e = 0; e < 16; ++e) {
            int p = fcol + e * 16;
            unsigned cv = X32[frow * XSTRD + p];
            float2 pwv = pwr[p];
            float2 cav = carrs[p];
            float fr2 = pwv.x * cav.x - pwv.y * cav.y;
            float fi2 = pwv.x * cav.y + pwv.y * cav.x;
            X32[frow * XSTRD + p] =
                packbf(bf2f(cv & 0xffffu) + fr2, bf2f(cv >> 16) + fi2);
        }
        __syncthreads();
    }

    // ---------------- GEMM2 (BM=32, BN=256, K=512), 16 panels BK=32 --------------
    // Barrier-free: wave-private slices; panel 0 was prestaged during the scan.
    {
        const char* W2 = (const char*)(ws + OFF_W2T);
        const char* Xb = (const char*)smem;
        floatx4 acc[2][2];
        #pragma unroll
        for (int i = 0; i < 2; ++i)
            #pragma unroll
            for (int j = 0; j < 2; ++j) acc[i][j] = (floatx4)0.0f;

        for (int t = 0; t < 16; ++t) {
            asm volatile("s_waitcnt vmcnt(0)" ::: "memory");   // panel t landed
            if (t < 15) {   // issue own slice of panel t+1
                char* dst = smem + B2_OFF + ((t + 1) & 1) * 16384 + wave * 2048;
                const char* src = W2 + (t + 1) * 64;
                #pragma unroll
                for (int i = 0; i < 2; ++i) {
                    int n = i * 64 + lane;
                    int R = wave * 32 + (n >> 2);
                    async16(src + (size_t)R * 1024 + (((n & 3) ^ fs) << 4), dst + n * 16);
                }
            }
            const char* bbuf = smem + B2_OFF + (t & 1) * 16384 + wave * 2048;
            const int kbA = t * 64 + q * 16;
            short8 a0 = *(const short8*)(Xb + rr * (XSTRS * 2) + kbA);
            short8 a1 = *(const short8*)(Xb + (16 + rr) * (XSTRS * 2) + kbA);
            #pragma unroll
            for (int j = 0; j < 2; ++j) {
                short8 b = *(const short8*)(bbuf + (j * 16 + rr) * 64 + ((q ^ fr) << 4));
                acc[0][j] = __builtin_amdgcn_mfma_f32_16x16x32_bf16(a0, b, acc[0][j], 0, 0, 0);
                acc[1][j] = __builtin_amdgcn_mfma_f32_16x16x32_bf16(a1, b, acc[1][j], 0, 0, 0);
            }
        }

        #pragma unroll
        for (int i = 0; i < 2; ++i) {
            int mbase = m0 + i * 16 + q * 4;
            #pragma unroll
            for (int j = 0; j < 2; ++j) {
                int col = wave * 32 + j * 16 + rr;
                #pragma unroll
                for (int r0 = 0; r0 < 4; ++r0) {
                    int rw = mbase + r0;
                    size_t gi = (size_t)rw * 256 + col;
                    out[gi] = acc[i][j][r0] + D[col] * u[gi];
                }
            }
        }
    }
}

extern "C" void kernel_launch(void* const* d_in, const int* in_sizes, int n_in,
                              void* d_out, int out_size, void* d_ws, size_t ws_size,
                              hipStream_t stream) {
    const float* u  = (const float*)d_in[0];
    const float* Lr = (const float*)d_in[1];
    const float* Li = (const float*)d_in[2];
    const float* Bm = (const float*)d_in[3];
    const float* Cm = (const float*)d_in[4];
    const float* D  = (const float*)d_in[5];
    const float* ls = (const float*)d_in[6];
    float* out = (float*)d_out;
    char* ws = (char*)d_ws;

    k_prep<<<512, 256, 0, stream>>>(Bm, Cm, Lr, Li, ls, ws);
    k_main<<<NCHUNK, 512, 81920, stream>>>(u, Lr, Li, ls, D, out, ws);
}